// Round 13
// baseline (99.008 us; speedup 1.0000x reference)
//
#include <hip/hip_runtime.h>
#include <math.h>

// Capsule dynamic routing v14 — v10 + HARD prefetch fence (sched_barrier).
// R12 synthesis: allocator grants ≈ min(128, 65536/T) VGPRs; T=512 grants 128
// but v10 compiled to 60 — the compiler sank my prefetch loads back to their
// uses to hit the 64-reg/8-wave tier, killing MLP (only ~2-3 loads in
// flight). v14 pins the pipeline: issue row j+1's 10 loads, then
// __builtin_amdgcn_sched_barrier(0) (nothing crosses), then FMA row j.
// Everything else is v10/v9 exactly (T=512, G=1, RPT=9, fused routing:
// no max pass — |logit|<=~40 is f32-safe; Z folded into s-reduction;
// one 5-float block reduction per iteration).
//
// x: [B=256, R=1152, I=8] f32
// W: [C=10, R=1152, I=8, O=16] f32
// out: [B=256, C=10, O=16] f32
//
// One block per (c,b). 512 threads = 128 groups of 4 lanes; 8 waves.
// Group g owns rows r = g + j*128 (j=0..8); lane q=t&3 owns o-quad.

#define C_CAPS 10
#define B_SZ   256
#define R_SZ   1152
#define I_SZ   8
#define O_SZ   16
#define T_THREADS 512
#define NGROUP 128       // T/4 groups
#define RPT 9            // rows per group = R / NGROUP
#define NW 8             // waves per block

__global__ __launch_bounds__(T_THREADS, 1) void capsule_kernel(
    const float* __restrict__ x,
    const float* __restrict__ w,
    float* __restrict__ out)
{
    const int c = blockIdx.x >> 8;        // / B_SZ
    const int b = blockIdx.x & 255;       // % B_SZ
    const int t = (int)threadIdx.x;
    const int lane = t & 63;
    const int wid = t >> 6;
    const int q = t & 3;                  // o-quad index
    const int g = t >> 2;                 // group id 0..127

    __shared__ float4 red_s[NW][4];       // per-wave s-partial, [wave][q]
    __shared__ float  red_z[NW];          // per-wave Z-partial
    __shared__ float4 s_fin[4];           // combined s per q
    __shared__ float  z_fin;              // combined Z

    // ---- priors with FENCED 1-row lookahead: P[j][k], rows r = g + j*128 ----
    float P[RPT][4];

    const float* xbase = x + ((size_t)b * R_SZ + g) * I_SZ;
    const float* wbase = w + ((size_t)c * R_SZ + g) * (I_SZ * O_SZ) + q * 4;
    const size_t xstep = (size_t)NGROUP * I_SZ;
    const size_t wstep = (size_t)NGROUP * I_SZ * O_SZ;

    // preload row j=0
    float4 xc0 = *(const float4*)(xbase);
    float4 xc1 = *(const float4*)(xbase + 4);
    float4 wc[8];
    #pragma unroll
    for (int i = 0; i < I_SZ; ++i) wc[i] = *(const float4*)(wbase + i * O_SZ);

    #pragma unroll
    for (int j = 0; j < RPT; ++j) {
        // issue row j+1's loads...
        float4 xn0, xn1, wn[8];
        if (j < RPT - 1) {
            const float* xp = xbase + (j + 1) * xstep;
            const float* wp = wbase + (j + 1) * wstep;
            xn0 = *(const float4*)(xp);
            xn1 = *(const float4*)(xp + 4);
            #pragma unroll
            for (int i = 0; i < I_SZ; ++i) wn[i] = *(const float4*)(wp + i * O_SZ);
        }
        // ...and PIN them before row j's FMAs: nothing may cross this fence,
        // so the compiler cannot sink the prefetch back to its use site.
        __builtin_amdgcn_sched_barrier(0);

        const float xi[I_SZ] = {xc0.x, xc0.y, xc0.z, xc0.w,
                                xc1.x, xc1.y, xc1.z, xc1.w};
        float a0 = 0.f, a1 = 0.f, a2 = 0.f, a3 = 0.f;
        #pragma unroll
        for (int i = 0; i < I_SZ; ++i) {
            a0 = fmaf(xi[i], wc[i].x, a0);
            a1 = fmaf(xi[i], wc[i].y, a1);
            a2 = fmaf(xi[i], wc[i].z, a2);
            a3 = fmaf(xi[i], wc[i].w, a3);
        }
        P[j][0] = a0; P[j][1] = a1; P[j][2] = a2; P[j][3] = a3;
        if (j < RPT - 1) {
            xc0 = xn0; xc1 = xn1;                 // full unroll renames: no movs
            #pragma unroll
            for (int i = 0; i < I_SZ; ++i) wc[i] = wn[i];
        }
    }

    float logit[RPT];
    #pragma unroll
    for (int j = 0; j < RPT; ++j) logit[j] = 0.0f;

    float vq[4];   // this lane's o-quad of the squashed output

    for (int it = 0; it < 3; ++it) {
        // ---- fused exp + weighted-sum partials (no max pass) ----
        float sa0 = 0.f, sa1 = 0.f, sa2 = 0.f, sa3 = 0.f, zp = 0.f;
        #pragma unroll
        for (int j = 0; j < RPT; ++j) {
            const float e = __expf(logit[j]);   // it==0: exp(0)=1 exactly
            zp += e;
            sa0 = fmaf(e, P[j][0], sa0);
            sa1 = fmaf(e, P[j][1], sa1);
            sa2 = fmaf(e, P[j][2], sa2);
            sa3 = fmaf(e, P[j][3], sa3);
        }
        // one reduction round: {sa0..3, zp} across the wave's 16 groups
        #pragma unroll
        for (int m = 4; m <= 32; m <<= 1) {
            sa0 += __shfl_xor(sa0, m, 64);
            sa1 += __shfl_xor(sa1, m, 64);
            sa2 += __shfl_xor(sa2, m, 64);
            sa3 += __shfl_xor(sa3, m, 64);
            zp  += __shfl_xor(zp,  m, 64);
        }
        if (lane < 4) red_s[wid][lane] = make_float4(sa0, sa1, sa2, sa3);
        if (lane == 0) red_z[wid] = zp;
        __syncthreads();

        // ---- one-wave combine (threads 0..4), then broadcast ----
        if (t < 4) {
            float4 a = red_s[0][t];
            #pragma unroll
            for (int ww = 1; ww < NW; ++ww) {
                const float4 rr = red_s[ww][t];
                a.x += rr.x; a.y += rr.y; a.z += rr.z; a.w += rr.w;
            }
            s_fin[t] = a;
        }
        if (t == 4) {
            float zz = red_z[0];
            #pragma unroll
            for (int ww = 1; ww < NW; ++ww) zz += red_z[ww];
            z_fin = zz;
        }
        __syncthreads();

        // ---- normalize + squash (normalize BEFORE squaring: overflow-safe) ----
        const float invZ = 1.0f / z_fin;
        const float4 sf = s_fin[q];
        const float u0 = sf.x * invZ, u1 = sf.y * invZ,
                    u2 = sf.z * invZ, u3 = sf.w * invZ;
        float nq = u0*u0 + u1*u1 + u2*u2 + u3*u3;
        nq += __shfl_xor(nq, 1, 64);
        nq += __shfl_xor(nq, 2, 64);
        const float scale = nq / ((1.0f + nq) * sqrtf(nq));
        vq[0] = scale * u0; vq[1] = scale * u1;
        vq[2] = scale * u2; vq[3] = scale * u3;

        // ---- logit update (iters 0,1): logit[r] += P[r]·v ----
        if (it < 2) {
            #pragma unroll
            for (int j = 0; j < RPT; ++j) {
                float d = P[j][0]*vq[0] + P[j][1]*vq[1]
                        + P[j][2]*vq[2] + P[j][3]*vq[3];
                d += __shfl_xor(d, 1, 64);
                d += __shfl_xor(d, 2, 64);
                logit[j] += d;
            }
        }
        // no end-of-iter barrier needed: red_s/red_z(it+1) writes occur only
        // after barrier #1(it+1); all s_fin(it) reads precede it. (v9 proof)
    }

    // ---- write out[b, c, :]: threads 0..3 hold quads 0..3 ----
    if (t < 4) {
        float* op = out + ((size_t)b * C_CAPS + c) * O_SZ + q * 4;
        *(float4*)op = make_float4(vq[0], vq[1], vq[2], vq[3]);
    }
}

extern "C" void kernel_launch(void* const* d_in, const int* in_sizes, int n_in,
                              void* d_out, int out_size, void* d_ws, size_t ws_size,
                              hipStream_t stream) {
    const float* x = (const float*)d_in[0];
    const float* w = (const float*)d_in[1];
    float* out = (float*)d_out;
    dim3 grid(C_CAPS * B_SZ);
    dim3 block(T_THREADS);
    hipLaunchKernelGGL(capsule_kernel, grid, block, 0, stream, x, w, out);
}

// Round 14
// 75.129 us; speedup vs baseline: 1.3178x; 1.3178x over previous
//
#include <hip/hip_runtime.h>
#include <math.h>

// Capsule dynamic routing v15 — TWO-KERNEL SPLIT.
// R8-R13 verdict: the fused kernel's floor is ~72us — each (c,b) block
// re-streams 576KB of W through L1 (5.9MB/CU), and no schedule/occupancy
// knob fixed it (compiler pins VGPR~60, sched_barrier regressed, dedup
// broke occupancy). Split the structure instead:
//   K1: priors GEMM with b-blocking — thread holds W[r,·,opair] in regs ONCE
//       and loops 64 b's; W read ~4x total (vs 256x). P stored bf16 in d_ws
//       (94MB, L3-resident), coalesced 256B/wave stores.
//   K2: v9/v10 routing (T=512, RPT=9, fused softmax: no max pass, Z folded,
//       one 5-float reduction/iter) fed by a 36KB contiguous bf16 P read
//       (512B/wave-inst) — per-CU input stream drops 5.9MB -> 360KB.
// Fallback: if ws_size < P bytes, launch the proven v10 single kernel.
//
// x: [B=256, R=1152, I=8] f32 ; W: [C=10, R=1152, I=8, O=16] f32
// out: [B=256, C=10, O=16] f32 ; P(ws): [C][B][R][O] bf16

#define C_CAPS 10
#define B_SZ   256
#define R_SZ   1152
#define I_SZ   8
#define O_SZ   16

// ---------------- K1: priors ----------------
// grid: C * (R/32) * 4 b-quarters = 10*36*4 = 1440 blocks, 256 threads.
// thread t: rl = t>>3 (row in tile, 0..31), op = t&7 (o-pair).
__global__ __launch_bounds__(256, 1) void priors_kernel(
    const float* __restrict__ x,
    const float* __restrict__ w,
    unsigned short* __restrict__ P)
{
    const int bid = blockIdx.x;
    const int c   = bid / 144;            // 144 = 36 rtiles * 4 bquads
    const int rem = bid - c * 144;
    const int rt  = rem >> 2;             // row tile 0..35
    const int bq  = rem & 3;              // b quarter
    const int t   = (int)threadIdx.x;
    const int rl  = t >> 3;               // 0..31
    const int op  = t & 7;                // o-pair 0..7
    const int r   = rt * 32 + rl;
    const int b0  = bq * 64;

    // one-time W load: W[c][r][i][op*2 .. +1] -> 16 regs
    const float* wbase = w + (((size_t)c * R_SZ + r) * I_SZ) * O_SZ + op * 2;
    float w0[I_SZ], w1[I_SZ];
    #pragma unroll
    for (int i = 0; i < I_SZ; ++i) {
        const float2 wv = *(const float2*)(wbase + i * O_SZ);
        w0[i] = wv.x; w1[i] = wv.y;
    }

    const float* xrow = x + ((size_t)b0 * R_SZ + r) * I_SZ;
    unsigned short* prow = P + (((size_t)c * B_SZ + b0) * R_SZ + r) * O_SZ + op * 2;

    #pragma unroll 2
    for (int bb = 0; bb < 64; ++bb) {
        const float4 xa = *(const float4*)(xrow);
        const float4 xb = *(const float4*)(xrow + 4);
        const float xi[I_SZ] = {xa.x, xa.y, xa.z, xa.w, xb.x, xb.y, xb.z, xb.w};
        float a0 = 0.f, a1 = 0.f;
        #pragma unroll
        for (int i = 0; i < I_SZ; ++i) {
            a0 = fmaf(xi[i], w0[i], a0);
            a1 = fmaf(xi[i], w1[i], a1);
        }
        // pack 2 x bf16 (round-to-nearest-even)
        unsigned int u0 = __float_as_uint(a0);
        unsigned int u1 = __float_as_uint(a1);
        u0 = (u0 + 0x7FFFu + ((u0 >> 16) & 1u)) >> 16;
        u1 = (u1 + 0x7FFFu + ((u1 >> 16) & 1u)) >> 16;
        *(unsigned int*)prow = u0 | (u1 << 16);
        xrow += (size_t)R_SZ * I_SZ;           // next b
        prow += (size_t)R_SZ * O_SZ;
    }
}

// ---------------- K2: routing ----------------
// One block per (c,b). 512 threads = 128 groups of 4 lanes; 8 waves.
// Group g owns rows r = g + j*128 (j=0..8); lane q=t&3 owns o-quad.
#define T2 512
#define NGROUP 128
#define RPT 9
#define NW 8

__global__ __launch_bounds__(T2, 1) void routing_kernel(
    const unsigned short* __restrict__ P,
    float* __restrict__ out)
{
    const int c = blockIdx.x >> 8;
    const int b = blockIdx.x & 255;
    const int t = (int)threadIdx.x;
    const int lane = t & 63;
    const int wid = t >> 6;
    const int q = t & 3;
    const int g = t >> 2;

    __shared__ float4 red_s[NW][4];
    __shared__ float  red_z[NW];
    __shared__ float4 s_fin[4];
    __shared__ float  z_fin;

    // ---- load priors (bf16 -> f32): contiguous 512B per wave-inst ----
    const unsigned short* pbase =
        P + (((size_t)c * B_SZ + b) * R_SZ + g) * O_SZ + q * 4;
    float Pr[RPT][4];
    #pragma unroll
    for (int j = 0; j < RPT; ++j) {
        const ushort4 pv = *(const ushort4*)(pbase + (size_t)j * NGROUP * O_SZ);
        Pr[j][0] = __uint_as_float((unsigned int)pv.x << 16);
        Pr[j][1] = __uint_as_float((unsigned int)pv.y << 16);
        Pr[j][2] = __uint_as_float((unsigned int)pv.z << 16);
        Pr[j][3] = __uint_as_float((unsigned int)pv.w << 16);
    }

    float logit[RPT];
    #pragma unroll
    for (int j = 0; j < RPT; ++j) logit[j] = 0.0f;

    float vq[4];

    for (int it = 0; it < 3; ++it) {
        // fused exp + weighted-sum partials (no max pass; |logit|<=~40 f32-safe)
        float sa0 = 0.f, sa1 = 0.f, sa2 = 0.f, sa3 = 0.f, zp = 0.f;
        #pragma unroll
        for (int j = 0; j < RPT; ++j) {
            const float e = __expf(logit[j]);
            zp += e;
            sa0 = fmaf(e, Pr[j][0], sa0);
            sa1 = fmaf(e, Pr[j][1], sa1);
            sa2 = fmaf(e, Pr[j][2], sa2);
            sa3 = fmaf(e, Pr[j][3], sa3);
        }
        #pragma unroll
        for (int m = 4; m <= 32; m <<= 1) {
            sa0 += __shfl_xor(sa0, m, 64);
            sa1 += __shfl_xor(sa1, m, 64);
            sa2 += __shfl_xor(sa2, m, 64);
            sa3 += __shfl_xor(sa3, m, 64);
            zp  += __shfl_xor(zp,  m, 64);
        }
        if (lane < 4) red_s[wid][lane] = make_float4(sa0, sa1, sa2, sa3);
        if (lane == 0) red_z[wid] = zp;
        __syncthreads();

        if (t < 4) {
            float4 a = red_s[0][t];
            #pragma unroll
            for (int ww = 1; ww < NW; ++ww) {
                const float4 rr = red_s[ww][t];
                a.x += rr.x; a.y += rr.y; a.z += rr.z; a.w += rr.w;
            }
            s_fin[t] = a;
        }
        if (t == 4) {
            float zz = red_z[0];
            #pragma unroll
            for (int ww = 1; ww < NW; ++ww) zz += red_z[ww];
            z_fin = zz;
        }
        __syncthreads();

        const float invZ = 1.0f / z_fin;
        const float4 sf = s_fin[q];
        const float u0 = sf.x * invZ, u1 = sf.y * invZ,
                    u2 = sf.z * invZ, u3 = sf.w * invZ;
        float nq = u0*u0 + u1*u1 + u2*u2 + u3*u3;
        nq += __shfl_xor(nq, 1, 64);
        nq += __shfl_xor(nq, 2, 64);
        const float scale = nq / ((1.0f + nq) * sqrtf(nq));
        vq[0] = scale * u0; vq[1] = scale * u1;
        vq[2] = scale * u2; vq[3] = scale * u3;

        if (it < 2) {
            #pragma unroll
            for (int j = 0; j < RPT; ++j) {
                float d = Pr[j][0]*vq[0] + Pr[j][1]*vq[1]
                        + Pr[j][2]*vq[2] + Pr[j][3]*vq[3];
                d += __shfl_xor(d, 1, 64);
                d += __shfl_xor(d, 2, 64);
                logit[j] += d;
            }
        }
        // no end-of-iter barrier: red_s/red_z(it+1) writes occur only after
        // barrier #1(it+1); all s_fin(it) reads precede it. (v9 proof)
    }

    if (t < 4) {
        float* op = out + ((size_t)b * C_CAPS + c) * O_SZ + q * 4;
        *(float4*)op = make_float4(vq[0], vq[1], vq[2], vq[3]);
    }
}

// ---------------- fallback: v10 fused single kernel (72.5us, proven) ----------------
__global__ __launch_bounds__(T2, 1) void capsule_fused_kernel(
    const float* __restrict__ x,
    const float* __restrict__ w,
    float* __restrict__ out)
{
    const int c = blockIdx.x >> 8;
    const int b = blockIdx.x & 255;
    const int t = (int)threadIdx.x;
    const int lane = t & 63;
    const int wid = t >> 6;
    const int q = t & 3;
    const int g = t >> 2;

    __shared__ float4 red_s[NW][4];
    __shared__ float  red_z[NW];
    __shared__ float4 s_fin[4];
    __shared__ float  z_fin;

    float P[RPT][4];
    const float* xbase = x + ((size_t)b * R_SZ + g) * I_SZ;
    const float* wbase = w + ((size_t)c * R_SZ + g) * (I_SZ * O_SZ) + q * 4;
    const size_t xstep = (size_t)NGROUP * I_SZ;
    const size_t wstep = (size_t)NGROUP * I_SZ * O_SZ;

    float4 xc0 = *(const float4*)(xbase);
    float4 xc1 = *(const float4*)(xbase + 4);
    float4 wc[8];
    #pragma unroll
    for (int i = 0; i < I_SZ; ++i) wc[i] = *(const float4*)(wbase + i * O_SZ);

    #pragma unroll
    for (int j = 0; j < RPT; ++j) {
        float4 xn0, xn1, wn[8];
        if (j < RPT - 1) {
            const float* xp = xbase + (j + 1) * xstep;
            const float* wp = wbase + (j + 1) * wstep;
            xn0 = *(const float4*)(xp);
            xn1 = *(const float4*)(xp + 4);
            #pragma unroll
            for (int i = 0; i < I_SZ; ++i) wn[i] = *(const float4*)(wp + i * O_SZ);
        }
        const float xi[I_SZ] = {xc0.x, xc0.y, xc0.z, xc0.w,
                                xc1.x, xc1.y, xc1.z, xc1.w};
        float a0 = 0.f, a1 = 0.f, a2 = 0.f, a3 = 0.f;
        #pragma unroll
        for (int i = 0; i < I_SZ; ++i) {
            a0 = fmaf(xi[i], wc[i].x, a0);
            a1 = fmaf(xi[i], wc[i].y, a1);
            a2 = fmaf(xi[i], wc[i].z, a2);
            a3 = fmaf(xi[i], wc[i].w, a3);
        }
        P[j][0] = a0; P[j][1] = a1; P[j][2] = a2; P[j][3] = a3;
        if (j < RPT - 1) {
            xc0 = xn0; xc1 = xn1;
            #pragma unroll
            for (int i = 0; i < I_SZ; ++i) wc[i] = wn[i];
        }
    }

    float logit[RPT];
    #pragma unroll
    for (int j = 0; j < RPT; ++j) logit[j] = 0.0f;
    float vq[4];

    for (int it = 0; it < 3; ++it) {
        float sa0 = 0.f, sa1 = 0.f, sa2 = 0.f, sa3 = 0.f, zp = 0.f;
        #pragma unroll
        for (int j = 0; j < RPT; ++j) {
            const float e = __expf(logit[j]);
            zp += e;
            sa0 = fmaf(e, P[j][0], sa0);
            sa1 = fmaf(e, P[j][1], sa1);
            sa2 = fmaf(e, P[j][2], sa2);
            sa3 = fmaf(e, P[j][3], sa3);
        }
        #pragma unroll
        for (int m = 4; m <= 32; m <<= 1) {
            sa0 += __shfl_xor(sa0, m, 64);
            sa1 += __shfl_xor(sa1, m, 64);
            sa2 += __shfl_xor(sa2, m, 64);
            sa3 += __shfl_xor(sa3, m, 64);
            zp  += __shfl_xor(zp,  m, 64);
        }
        if (lane < 4) red_s[wid][lane] = make_float4(sa0, sa1, sa2, sa3);
        if (lane == 0) red_z[wid] = zp;
        __syncthreads();
        if (t < 4) {
            float4 a = red_s[0][t];
            #pragma unroll
            for (int ww = 1; ww < NW; ++ww) {
                const float4 rr = red_s[ww][t];
                a.x += rr.x; a.y += rr.y; a.z += rr.z; a.w += rr.w;
            }
            s_fin[t] = a;
        }
        if (t == 4) {
            float zz = red_z[0];
            #pragma unroll
            for (int ww = 1; ww < NW; ++ww) zz += red_z[ww];
            z_fin = zz;
        }
        __syncthreads();
        const float invZ = 1.0f / z_fin;
        const float4 sf = s_fin[q];
        const float u0 = sf.x * invZ, u1 = sf.y * invZ,
                    u2 = sf.z * invZ, u3 = sf.w * invZ;
        float nq = u0*u0 + u1*u1 + u2*u2 + u3*u3;
        nq += __shfl_xor(nq, 1, 64);
        nq += __shfl_xor(nq, 2, 64);
        const float scale = nq / ((1.0f + nq) * sqrtf(nq));
        vq[0] = scale * u0; vq[1] = scale * u1;
        vq[2] = scale * u2; vq[3] = scale * u3;
        if (it < 2) {
            #pragma unroll
            for (int j = 0; j < RPT; ++j) {
                float d = P[j][0]*vq[0] + P[j][1]*vq[1]
                        + P[j][2]*vq[2] + P[j][3]*vq[3];
                d += __shfl_xor(d, 1, 64);
                d += __shfl_xor(d, 2, 64);
                logit[j] += d;
            }
        }
    }

    if (t < 4) {
        float* op = out + ((size_t)b * C_CAPS + c) * O_SZ + q * 4;
        *(float4*)op = make_float4(vq[0], vq[1], vq[2], vq[3]);
    }
}

extern "C" void kernel_launch(void* const* d_in, const int* in_sizes, int n_in,
                              void* d_out, int out_size, void* d_ws, size_t ws_size,
                              hipStream_t stream) {
    const float* x = (const float*)d_in[0];
    const float* w = (const float*)d_in[1];
    float* out = (float*)d_out;

    const size_t pbytes = (size_t)C_CAPS * B_SZ * R_SZ * O_SZ * 2;  // 94.4 MB bf16
    if (ws_size >= pbytes) {
        unsigned short* P = (unsigned short*)d_ws;
        hipLaunchKernelGGL(priors_kernel, dim3(C_CAPS * 36 * 4), dim3(256),
                           0, stream, x, w, P);
        hipLaunchKernelGGL(routing_kernel, dim3(C_CAPS * B_SZ), dim3(T2),
                           0, stream, P, out);
    } else {
        hipLaunchKernelGGL(capsule_fused_kernel, dim3(C_CAPS * B_SZ), dim3(T2),
                           0, stream, x, w, out);
    }
}

// Round 15
// 63.378 us; speedup vs baseline: 1.5622x; 1.1854x over previous
//
#include <hip/hip_runtime.h>
#include <math.h>

// Capsule dynamic routing v16 — split, tuned per R14 counters.
// K1 (priors): was write-issue-bound (dword stores, 256B/wave-inst, 2.4TB/s).
//   Now: thread owns (row, o-half=8 o's): 64 W regs held across a 32-b loop,
//   stores uint4 = 16B/lane -> 1KB contiguous per wave-inst. P stored fp16
//   (1-inst cvt; 8x better mantissa than bf16 -> absmax margin back).
// K2 (routing): was barrier/serial-combine-bound (6 barriers + 5-thread
//   serial section per block). Now: double-buffered partials by iteration
//   parity -> ONE barrier/iter (3 total); every thread combines the 8 wave
//   partials itself (8 broadcast LDS reads, conflict-free).
//   Proof: buf[i&1] reads happen between barrier(i) and barrier(i+1); it is
//   rewritten only in iter i+2, after barrier(i+1). No race.
// Fallback: proven v10 fused kernel if ws_size < P bytes.
//
// x: [B=256, R=1152, I=8] f32 ; W: [C=10, R=1152, I=8, O=16] f32
// out: [B=256, C=10, O=16] f32 ; P(ws): [C][B][R][O] fp16

#define C_CAPS 10
#define B_SZ   256
#define R_SZ   1152
#define I_SZ   8
#define O_SZ   16

static __device__ __forceinline__ unsigned int pack2h(float a, float b) {
    const _Float16 ha = (_Float16)a, hb = (_Float16)b;
    const unsigned short ua = __builtin_bit_cast(unsigned short, ha);
    const unsigned short ub = __builtin_bit_cast(unsigned short, hb);
    return (unsigned int)ua | ((unsigned int)ub << 16);
}
static __device__ __forceinline__ float h2f(unsigned short u) {
    const _Float16 h = __builtin_bit_cast(_Float16, u);
    return (float)h;
}

// ---------------- K1: priors ----------------
// grid: C * (R/128=9) * (B/32=8) = 720 blocks, 256 threads.
// thread t: rl = t>>1 (row 0..127), oh = t&1 (o-half). Loops 32 batches.
#define RTILE 128
#define BBLK  32
__global__ __launch_bounds__(256, 1) void priors_kernel(
    const float* __restrict__ x,
    const float* __restrict__ w,
    unsigned short* __restrict__ P)
{
    const int bid = blockIdx.x;
    const int c   = bid / 72;             // 72 = 9 rtiles * 8 bgroups
    const int rem = bid - c * 72;
    const int rt  = rem >> 3;             // row tile 0..8
    const int bg  = rem & 7;              // b group 0..7
    const int t   = (int)threadIdx.x;
    const int rl  = t >> 1;               // 0..127
    const int oh  = t & 1;                // o-half
    const int r   = rt * RTILE + rl;
    const int b0  = bg * BBLK;

    // one-time W load: W[c][r][i][oh*8 .. +7] -> 64 regs
    const float* wb = w + (((size_t)c * R_SZ + r) * I_SZ) * O_SZ + oh * 8;
    float W0[I_SZ][8];
    #pragma unroll
    for (int i = 0; i < I_SZ; ++i) {
        const float4 a = *(const float4*)(wb + i * O_SZ);
        const float4 bv = *(const float4*)(wb + i * O_SZ + 4);
        W0[i][0] = a.x;  W0[i][1] = a.y;  W0[i][2] = a.z;  W0[i][3] = a.w;
        W0[i][4] = bv.x; W0[i][5] = bv.y; W0[i][6] = bv.z; W0[i][7] = bv.w;
    }

    const float* xr = x + ((size_t)b0 * R_SZ + r) * I_SZ;
    unsigned int* pr = (unsigned int*)
        (P + (((size_t)c * B_SZ + b0) * R_SZ + r) * O_SZ + oh * 8);
    const size_t xstep = (size_t)R_SZ * I_SZ;        // floats per b
    const size_t pstep = (size_t)R_SZ * O_SZ / 2;    // uints per b

    for (int bb = 0; bb < BBLK; ++bb) {
        const float4 xa = *(const float4*)(xr);
        const float4 xb = *(const float4*)(xr + 4);
        const float xi[I_SZ] = {xa.x, xa.y, xa.z, xa.w, xb.x, xb.y, xb.z, xb.w};
        float acc[8];
        #pragma unroll
        for (int k = 0; k < 8; ++k) acc[k] = 0.0f;
        #pragma unroll
        for (int i = 0; i < I_SZ; ++i) {
            #pragma unroll
            for (int k = 0; k < 8; ++k)
                acc[k] = fmaf(xi[i], W0[i][k], acc[k]);
        }
        uint4 o;
        o.x = pack2h(acc[0], acc[1]);
        o.y = pack2h(acc[2], acc[3]);
        o.z = pack2h(acc[4], acc[5]);
        o.w = pack2h(acc[6], acc[7]);
        *(uint4*)pr = o;                 // 16B/lane -> 1KB/wave-inst contiguous
        xr += xstep;
        pr += pstep;
    }
}

// ---------------- K2: routing ----------------
// One block per (c,b). 512 threads = 128 groups of 4 lanes; 8 waves.
// Group g owns rows r = g + j*128 (j=0..8); lane q=t&3 owns o-quad.
#define T2 512
#define NGROUP 128
#define RPT 9
#define NW 8

__global__ __launch_bounds__(T2, 1) void routing_kernel(
    const unsigned short* __restrict__ P,
    float* __restrict__ out)
{
    const int c = blockIdx.x >> 8;
    const int b = blockIdx.x & 255;
    const int t = (int)threadIdx.x;
    const int lane = t & 63;
    const int wid = t >> 6;
    const int q = t & 3;
    const int g = t >> 2;

    __shared__ float4 red_s[2][NW][4];   // double-buffered by iter parity
    __shared__ float  red_z[2][NW];

    // ---- load priors (fp16 -> f32): contiguous 512B per wave-inst ----
    const unsigned short* pbase =
        P + (((size_t)c * B_SZ + b) * R_SZ + g) * O_SZ + q * 4;
    float Pr[RPT][4];
    #pragma unroll
    for (int j = 0; j < RPT; ++j) {
        const ushort4 pv = *(const ushort4*)(pbase + (size_t)j * NGROUP * O_SZ);
        Pr[j][0] = h2f(pv.x);
        Pr[j][1] = h2f(pv.y);
        Pr[j][2] = h2f(pv.z);
        Pr[j][3] = h2f(pv.w);
    }

    float logit[RPT];
    #pragma unroll
    for (int j = 0; j < RPT; ++j) logit[j] = 0.0f;

    float vq[4];

    for (int it = 0; it < 3; ++it) {
        const int pb = it & 1;
        // fused exp + weighted-sum partials (no max pass; |logit|<=~40 f32-safe)
        float sa0 = 0.f, sa1 = 0.f, sa2 = 0.f, sa3 = 0.f, zp = 0.f;
        #pragma unroll
        for (int j = 0; j < RPT; ++j) {
            const float e = __expf(logit[j]);
            zp += e;
            sa0 = fmaf(e, Pr[j][0], sa0);
            sa1 = fmaf(e, Pr[j][1], sa1);
            sa2 = fmaf(e, Pr[j][2], sa2);
            sa3 = fmaf(e, Pr[j][3], sa3);
        }
        #pragma unroll
        for (int m = 4; m <= 32; m <<= 1) {
            sa0 += __shfl_xor(sa0, m, 64);
            sa1 += __shfl_xor(sa1, m, 64);
            sa2 += __shfl_xor(sa2, m, 64);
            sa3 += __shfl_xor(sa3, m, 64);
            zp  += __shfl_xor(zp,  m, 64);
        }
        if (lane < 4) red_s[pb][wid][lane] = make_float4(sa0, sa1, sa2, sa3);
        if (lane == 0) red_z[pb][wid] = zp;
        __syncthreads();                       // the ONLY barrier this iter

        // ---- every thread combines the 8 wave partials (broadcast reads) ----
        float4 sf = red_s[pb][0][q];
        float Z = red_z[pb][0];
        #pragma unroll
        for (int ww = 1; ww < NW; ++ww) {
            const float4 rr = red_s[pb][ww][q];
            sf.x += rr.x; sf.y += rr.y; sf.z += rr.z; sf.w += rr.w;
            Z += red_z[pb][ww];
        }

        // ---- normalize + squash (normalize BEFORE squaring: overflow-safe) ----
        const float invZ = 1.0f / Z;
        const float u0 = sf.x * invZ, u1 = sf.y * invZ,
                    u2 = sf.z * invZ, u3 = sf.w * invZ;
        float nq = u0*u0 + u1*u1 + u2*u2 + u3*u3;
        nq += __shfl_xor(nq, 1, 64);
        nq += __shfl_xor(nq, 2, 64);
        const float scale = nq / ((1.0f + nq) * sqrtf(nq));
        vq[0] = scale * u0; vq[1] = scale * u1;
        vq[2] = scale * u2; vq[3] = scale * u3;

        // ---- logit update (iters 0,1): logit[r] += P[r]·v ----
        if (it < 2) {
            #pragma unroll
            for (int j = 0; j < RPT; ++j) {
                float d = Pr[j][0]*vq[0] + Pr[j][1]*vq[1]
                        + Pr[j][2]*vq[2] + Pr[j][3]*vq[3];
                d += __shfl_xor(d, 1, 64);
                d += __shfl_xor(d, 2, 64);
                logit[j] += d;
            }
        }
    }

    if (t < 4) {
        float* op = out + ((size_t)b * C_CAPS + c) * O_SZ + q * 4;
        *(float4*)op = make_float4(vq[0], vq[1], vq[2], vq[3]);
    }
}

// ---------------- fallback: v10 fused single kernel (72.5us, proven) ----------------
__global__ __launch_bounds__(T2, 1) void capsule_fused_kernel(
    const float* __restrict__ x,
    const float* __restrict__ w,
    float* __restrict__ out)
{
    const int c = blockIdx.x >> 8;
    const int b = blockIdx.x & 255;
    const int t = (int)threadIdx.x;
    const int lane = t & 63;
    const int wid = t >> 6;
    const int q = t & 3;
    const int g = t >> 2;

    __shared__ float4 red_s[NW][4];
    __shared__ float  red_z[NW];
    __shared__ float4 s_fin[4];
    __shared__ float  z_fin;

    float Pf[RPT][4];
    const float* xbase = x + ((size_t)b * R_SZ + g) * I_SZ;
    const float* wbase = w + ((size_t)c * R_SZ + g) * (I_SZ * O_SZ) + q * 4;
    const size_t xstep = (size_t)NGROUP * I_SZ;
    const size_t wstep = (size_t)NGROUP * I_SZ * O_SZ;

    float4 xc0 = *(const float4*)(xbase);
    float4 xc1 = *(const float4*)(xbase + 4);
    float4 wc[8];
    #pragma unroll
    for (int i = 0; i < I_SZ; ++i) wc[i] = *(const float4*)(wbase + i * O_SZ);

    #pragma unroll
    for (int j = 0; j < RPT; ++j) {
        float4 xn0, xn1, wn[8];
        if (j < RPT - 1) {
            const float* xp = xbase + (j + 1) * xstep;
            const float* wp = wbase + (j + 1) * wstep;
            xn0 = *(const float4*)(xp);
            xn1 = *(const float4*)(xp + 4);
            #pragma unroll
            for (int i = 0; i < I_SZ; ++i) wn[i] = *(const float4*)(wp + i * O_SZ);
        }
        const float xi[I_SZ] = {xc0.x, xc0.y, xc0.z, xc0.w,
                                xc1.x, xc1.y, xc1.z, xc1.w};
        float a0 = 0.f, a1 = 0.f, a2 = 0.f, a3 = 0.f;
        #pragma unroll
        for (int i = 0; i < I_SZ; ++i) {
            a0 = fmaf(xi[i], wc[i].x, a0);
            a1 = fmaf(xi[i], wc[i].y, a1);
            a2 = fmaf(xi[i], wc[i].z, a2);
            a3 = fmaf(xi[i], wc[i].w, a3);
        }
        Pf[j][0] = a0; Pf[j][1] = a1; Pf[j][2] = a2; Pf[j][3] = a3;
        if (j < RPT - 1) {
            xc0 = xn0; xc1 = xn1;
            #pragma unroll
            for (int i = 0; i < I_SZ; ++i) wc[i] = wn[i];
        }
    }

    float logit[RPT];
    #pragma unroll
    for (int j = 0; j < RPT; ++j) logit[j] = 0.0f;
    float vq[4];

    for (int it = 0; it < 3; ++it) {
        float sa0 = 0.f, sa1 = 0.f, sa2 = 0.f, sa3 = 0.f, zp = 0.f;
        #pragma unroll
        for (int j = 0; j < RPT; ++j) {
            const float e = __expf(logit[j]);
            zp += e;
            sa0 = fmaf(e, Pf[j][0], sa0);
            sa1 = fmaf(e, Pf[j][1], sa1);
            sa2 = fmaf(e, Pf[j][2], sa2);
            sa3 = fmaf(e, Pf[j][3], sa3);
        }
        #pragma unroll
        for (int m = 4; m <= 32; m <<= 1) {
            sa0 += __shfl_xor(sa0, m, 64);
            sa1 += __shfl_xor(sa1, m, 64);
            sa2 += __shfl_xor(sa2, m, 64);
            sa3 += __shfl_xor(sa3, m, 64);
            zp  += __shfl_xor(zp,  m, 64);
        }
        if (lane < 4) red_s[wid][lane] = make_float4(sa0, sa1, sa2, sa3);
        if (lane == 0) red_z[wid] = zp;
        __syncthreads();
        if (t < 4) {
            float4 a = red_s[0][t];
            #pragma unroll
            for (int ww = 1; ww < NW; ++ww) {
                const float4 rr = red_s[ww][t];
                a.x += rr.x; a.y += rr.y; a.z += rr.z; a.w += rr.w;
            }
            s_fin[t] = a;
        }
        if (t == 4) {
            float zz = red_z[0];
            #pragma unroll
            for (int ww = 1; ww < NW; ++ww) zz += red_z[ww];
            z_fin = zz;
        }
        __syncthreads();
        const float invZ = 1.0f / z_fin;
        const float4 sf = s_fin[q];
        const float u0 = sf.x * invZ, u1 = sf.y * invZ,
                    u2 = sf.z * invZ, u3 = sf.w * invZ;
        float nq = u0*u0 + u1*u1 + u2*u2 + u3*u3;
        nq += __shfl_xor(nq, 1, 64);
        nq += __shfl_xor(nq, 2, 64);
        const float scale = nq / ((1.0f + nq) * sqrtf(nq));
        vq[0] = scale * u0; vq[1] = scale * u1;
        vq[2] = scale * u2; vq[3] = scale * u3;
        if (it < 2) {
            #pragma unroll
            for (int j = 0; j < RPT; ++j) {
                float d = Pf[j][0]*vq[0] + Pf[j][1]*vq[1]
                        + Pf[j][2]*vq[2] + Pf[j][3]*vq[3];
                d += __shfl_xor(d, 1, 64);
                d += __shfl_xor(d, 2, 64);
                logit[j] += d;
            }
        }
    }

    if (t < 4) {
        float* op = out + ((size_t)b * C_CAPS + c) * O_SZ + q * 4;
        *(float4*)op = make_float4(vq[0], vq[1], vq[2], vq[3]);
    }
}

extern "C" void kernel_launch(void* const* d_in, const int* in_sizes, int n_in,
                              void* d_out, int out_size, void* d_ws, size_t ws_size,
                              hipStream_t stream) {
    const float* x = (const float*)d_in[0];
    const float* w = (const float*)d_in[1];
    float* out = (float*)d_out;

    const size_t pbytes = (size_t)C_CAPS * B_SZ * R_SZ * O_SZ * 2;  // 94.4 MB fp16
    if (ws_size >= pbytes) {
        unsigned short* P = (unsigned short*)d_ws;
        hipLaunchKernelGGL(priors_kernel, dim3(C_CAPS * 9 * 8), dim3(256),
                           0, stream, x, w, P);
        hipLaunchKernelGGL(routing_kernel, dim3(C_CAPS * B_SZ), dim3(T2),
                           0, stream, P, out);
    } else {
        hipLaunchKernelGGL(capsule_fused_kernel, dim3(C_CAPS * B_SZ), dim3(T2),
                           0, stream, x, w, out);
    }
}